// Round 2
// baseline (46.857 us; speedup 1.0000x reference)
//
#include <hip/hip_runtime.h>
#include <stdint.h>

// BERT input representation, round 2: operand-swapped MFMA GEMM.
//   out = x@W_emb + seg + b_emb*(1+Sw) + b_seg + PE
// B=64 S=512 F=64 D=1024 SEG=8 -> GEMM M=32768 K=64 N=1024.
//
// Design:
//  setup kernel (one launch, writes d_ws):
//    [0, 128KB)        W in bf16 A-fragment order (per 16-col frag x kf x lane x 8)
//    [128KB, 128KB+2MB) pe2[s][c] = PE(s,c) + b_emb[c]*(1+Sw) + b_seg  (f32)
//    [+2MB, +4MB)      x as bf16 row-major [32768][64]
//  main kernel: no LDS, no barriers. mfma(W_frag, x_frag) puts 4 CONSECUTIVE
//  output cols in each lane's f32x4 -> float4 stores. Segment reduce via
//  shfl_xor butterfly over 8-lane groups (rows are lane-indexed now).

typedef __attribute__((ext_vector_type(8))) short short8;
typedef __attribute__((ext_vector_type(4))) float f32x4;

#define D_DIM 1024
#define WS_PE_OFF 131072
#define WS_X_OFF (131072 + 2097152)

__device__ __forceinline__ unsigned short f2bf(float f) {
  unsigned u = __float_as_uint(f);
  u = (u + 0x7FFFu + ((u >> 16) & 1u)) >> 16;  // RNE f32 -> bf16
  return (unsigned short)u;
}

__global__ __launch_bounds__(256) void bert_setup_kernel(
    const float* __restrict__ x, const float* __restrict__ W,
    const float* __restrict__ b_emb, const float* __restrict__ w_seg,
    const float* __restrict__ b_seg, unsigned short* __restrict__ wsW,
    float* __restrict__ wsPE, unsigned short* __restrict__ wsX) {
  const int bid = blockIdx.x;
  const int tid = threadIdx.x;
  if (bid < 1024) {
    // ---- x f32 -> bf16, 8 elems/thread (262144 threads) ----
    const int t = bid * 256 + tid;
    const float4* p = reinterpret_cast<const float4*>(x) + (size_t)t * 2;
    float4 v0 = p[0], v1 = p[1];
    short8 o;
    o[0] = (short)f2bf(v0.x); o[1] = (short)f2bf(v0.y);
    o[2] = (short)f2bf(v0.z); o[3] = (short)f2bf(v0.w);
    o[4] = (short)f2bf(v1.x); o[5] = (short)f2bf(v1.y);
    o[6] = (short)f2bf(v1.z); o[7] = (short)f2bf(v1.w);
    *reinterpret_cast<short8*>(wsX + (size_t)t * 8) = o;
  } else if (bid < 3072) {
    // ---- pe2[s][c] = PE + b_emb[c]*(1+Sw) + b_seg (524288 threads) ----
    const int t = (bid - 1024) * 256 + tid;
    const int s = t >> 10;
    const int c = t & 1023;
    float Sw = 0.f;
#pragma unroll
    for (int i = 0; i < 8; ++i) Sw += w_seg[i];
    const float inv2pi = 0.15915494309189535f;
    const float KLOG = 0.02595256324130752f;  // log2(10000)/512
    float divrev = exp2f(-(float)(c >> 1) * KLOG) * inv2pi;
    float rev = (float)s * divrev + ((c & 1) ? 0.25f : 0.f);
    rev = rev - floorf(rev);
    float pe = __builtin_amdgcn_sinf(rev);
    wsPE[t] = pe + b_emb[c] * (1.f + Sw) + b_seg[0];
  } else {
    // ---- W -> bf16 A-fragment layout (8192 threads, 8 elems each) ----
    // t = (cf*2 + kf)*64 + lane ; value i = W[kf*32 + (lane>>4)*8 + i][cf*16 + (lane&15)]
    const int t = (bid - 3072) * 256 + tid;
    const int cf = t >> 7;
    const int kf = (t >> 6) & 1;
    const int lane = t & 63;
    const int col = cf * 16 + (lane & 15);
    const int k0 = kf * 32 + ((lane >> 4) << 3);
    short8 o;
#pragma unroll
    for (int i = 0; i < 8; ++i)
      o[i] = (short)f2bf(W[(size_t)(k0 + i) * D_DIM + col]);
    *reinterpret_cast<short8*>(wsW + (size_t)t * 8) = o;
  }
}

__global__ __launch_bounds__(256) void bert_main_kernel(
    const unsigned short* __restrict__ wsX,
    const unsigned short* __restrict__ wsW, const float* __restrict__ wsPE,
    const float* __restrict__ w_seg, float* __restrict__ out) {
  const int tid = threadIdx.x;
  const int lane = tid & 63;
  const int wave = tid >> 6;
  const int bid = blockIdx.x;
  // XCD swizzle: the 8 nblks sharing an mblk land on the same XCD (bid%8 const)
  const int nblk = (bid >> 3) & 7;
  const int mblk = (bid & 7) | ((bid >> 6) << 3);
  const int mbase = mblk * 64;
  const int nbase = nblk * 128;
  const int mw = wave >> 1;  // row half of block (32 rows)
  const int nw = wave & 1;   // col half of block (64 cols)
  const int L15 = lane & 15;
  const int g = lane >> 4;

  // ---- A fragments: W cols (M dim). Linear, coalesced, L2-hot. ----
  short8 aW[4][2];
#pragma unroll
  for (int cf = 0; cf < 4; ++cf) {
#pragma unroll
    for (int kf = 0; kf < 2; ++kf) {
      const int cfg = (nbase >> 4) + nw * 4 + cf;  // global 16-col frag idx
      aW[cf][kf] = *reinterpret_cast<const short8*>(
          wsW + ((size_t)(cfg * 2 + kf) * 64 + lane) * 8);
    }
  }

  // ---- B fragments: x rows (N dim). 16 rows x 64B per fragment. ----
  short8 bX[2][2];
#pragma unroll
  for (int rf = 0; rf < 2; ++rf) {
#pragma unroll
    for (int kf = 0; kf < 2; ++kf) {
      const int row = mbase + mw * 32 + rf * 16 + L15;
      bX[rf][kf] = *reinterpret_cast<const short8*>(
          wsX + (size_t)row * 64 + kf * 32 + g * 8);
    }
  }

  // ---- MFMA: D[m=out-col][n=out-row] ----
  f32x4 acc[4][2];
#pragma unroll
  for (int cf = 0; cf < 4; ++cf) {
#pragma unroll
    for (int rf = 0; rf < 2; ++rf) {
      f32x4 c = {0.f, 0.f, 0.f, 0.f};
      c = __builtin_amdgcn_mfma_f32_16x16x32_bf16(aW[cf][0], bX[rf][0], c, 0,
                                                  0, 0);
      c = __builtin_amdgcn_mfma_f32_16x16x32_bf16(aW[cf][1], bX[rf][1], c, 0,
                                                  0, 0);
      acc[cf][rf] = c;
    }
  }

  // ---- fused epilogue ----
  const float t = w_seg[lane & 7];  // row position within segment = lane&7

#pragma unroll
  for (int cf = 0; cf < 4; ++cf) {
#pragma unroll
    for (int rf = 0; rf < 2; ++rf) {
      f32x4 a = acc[cf][rf];
      // segment value: sum w[r]*acc over the 8 rows in this lane's 8-group
      float q0 = a[0] * t, q1 = a[1] * t, q2 = a[2] * t, q3 = a[3] * t;
      q0 += __shfl_xor(q0, 1); q1 += __shfl_xor(q1, 1);
      q2 += __shfl_xor(q2, 1); q3 += __shfl_xor(q3, 1);
      q0 += __shfl_xor(q0, 2); q1 += __shfl_xor(q1, 2);
      q2 += __shfl_xor(q2, 2); q3 += __shfl_xor(q3, 2);
      q0 += __shfl_xor(q0, 4); q1 += __shfl_xor(q1, 4);
      q2 += __shfl_xor(q2, 4); q3 += __shfl_xor(q3, 4);

      const int row = mbase + mw * 32 + rf * 16 + L15;
      const int s = row & 511;
      const int colq = nbase + nw * 64 + cf * 16 + g * 4;
      const float4 pe4 =
          *reinterpret_cast<const float4*>(wsPE + (size_t)s * D_DIM + colq);
      float4 o;
      o.x = a[0] + q0 + pe4.x;
      o.y = a[1] + q1 + pe4.y;
      o.z = a[2] + q2 + pe4.z;
      o.w = a[3] + q3 + pe4.w;
      *reinterpret_cast<float4*>(out + (size_t)row * D_DIM + colq) = o;
    }
  }
}

extern "C" void kernel_launch(void* const* d_in, const int* in_sizes, int n_in,
                              void* d_out, int out_size, void* d_ws,
                              size_t ws_size, hipStream_t stream) {
  const float* x = (const float*)d_in[0];
  const float* W = (const float*)d_in[1];
  const float* b_emb = (const float*)d_in[2];
  const float* w_seg = (const float*)d_in[3];
  const float* b_seg = (const float*)d_in[4];
  float* out = (float*)d_out;

  unsigned short* wsW = (unsigned short*)d_ws;
  float* wsPE = (float*)((char*)d_ws + WS_PE_OFF);
  unsigned short* wsX = (unsigned short*)((char*)d_ws + WS_X_OFF);

  bert_setup_kernel<<<3104, 256, 0, stream>>>(x, W, b_emb, w_seg, b_seg, wsW,
                                              wsPE, wsX);
  bert_main_kernel<<<4096, 256, 0, stream>>>(wsX, wsW, wsPE, w_seg, out);
}